// Round 9
// baseline (362.575 us; speedup 1.0000x reference)
//
#include <hip/hip_runtime.h>

#define N_NODES   100000
#define N_EDGES   1600000
#define NFEAT     128
#define NGRAPHS   2048
#define CBSHIFT   8                        // 256 nodes per coarse bucket
#define NCB       ((N_NODES + 255) / 256)  // 391
#define P1_EPB    2048                     // edges per k_p1 block
#define DP_BLOCKS 25
#define DP_NPB    ((N_NODES + DP_BLOCKS - 1) / DP_BLOCKS)   // 4000 nodes/block

typedef __attribute__((ext_vector_type(8))) short short8;   // 8 bf16 = 4 VGPRs
typedef __attribute__((ext_vector_type(4))) float f32x4;

// RNE float -> bf16 (finite inputs)
__device__ __forceinline__ unsigned short f2bf(float f) {
    unsigned int u = __float_as_uint(f);
    u += 0x7FFFu + ((u >> 16) & 1u);
    return (unsigned short)(u >> 16);
}

// accumulate 8 bf16 (packed in uint4) into 8 fp32
__device__ __forceinline__ void acc8(float* acc, uint4 v) {
    acc[0] += __uint_as_float(v.x << 16);
    acc[1] += __uint_as_float(v.x & 0xFFFF0000u);
    acc[2] += __uint_as_float(v.y << 16);
    acc[3] += __uint_as_float(v.y & 0xFFFF0000u);
    acc[4] += __uint_as_float(v.z << 16);
    acc[5] += __uint_as_float(v.z & 0xFFFF0000u);
    acc[6] += __uint_as_float(v.w << 16);
    acc[7] += __uint_as_float(v.w & 0xFFFF0000u);
}

// ---------------- coarse bucket histogram (LDS-aggregated) ----------------
__global__ __launch_bounds__(256) void k_bhist(const int* __restrict__ dst,
                                               int* __restrict__ bcount) {
    __shared__ int h[NCB];
    for (int i = threadIdx.x; i < NCB; i += 256) h[i] = 0;
    __syncthreads();
    int stride = gridDim.x * 256;
    for (int e = blockIdx.x * 256 + threadIdx.x; e < N_EDGES; e += stride)
        atomicAdd(&h[dst[e] >> CBSHIFT], 1);
    __syncthreads();
    for (int i = threadIdx.x; i < NCB; i += 256) {
        int v = h[i];
        if (v) atomicAdd(&bcount[i], v);
    }
}

// ---------------- scan of 391 bucket counts -> bstart, gcur ----------------
__global__ __launch_bounds__(256) void k_bscan(const int* __restrict__ bcount,
                                               int* __restrict__ bstart,
                                               int* __restrict__ gcur) {
    __shared__ int s[256];
    const int t = threadIdx.x;
    int v0 = (2 * t < NCB) ? bcount[2 * t] : 0;
    int v1 = (2 * t + 1 < NCB) ? bcount[2 * t + 1] : 0;
    int local = v0 + v1;
    s[t] = local;
    __syncthreads();
    for (int off = 1; off < 256; off <<= 1) {
        int x = (t >= off) ? s[t - off] : 0;
        __syncthreads();
        s[t] += x;
        __syncthreads();
    }
    int excl = s[t] - local;
    if (2 * t < NCB)     { bstart[2 * t] = excl;          gcur[2 * t] = excl; }
    if (2 * t + 1 < NCB) { bstart[2 * t + 1] = excl + v0; gcur[2 * t + 1] = excl + v0; }
    if (t == 255) bstart[NCB] = s[255];
}

// ---------------- pass 1: block-ranked scatter into coarse bucket regions ----------------
// pairs[pos] = src | (dlocal << 17), dlocal in [0,256)
__global__ __launch_bounds__(256) void k_p1(const int* __restrict__ src,
                                            const int* __restrict__ dst,
                                            int* __restrict__ gcur,
                                            unsigned int* __restrict__ pairs) {
    __shared__ int hist[NCB], base[NCB], cur[NCB];
    for (int i = threadIdx.x; i < NCB; i += 256) { hist[i] = 0; cur[i] = 0; }
    __syncthreads();
    const int e0 = blockIdx.x * P1_EPB;
    const int e1 = min(e0 + P1_EPB, N_EDGES);
    for (int e = e0 + threadIdx.x; e < e1; e += 256)
        atomicAdd(&hist[dst[e] >> CBSHIFT], 1);
    __syncthreads();
    for (int i = threadIdx.x; i < NCB; i += 256) {
        int c = hist[i];
        base[i] = c ? atomicAdd(&gcur[i], c) : 0;
    }
    __syncthreads();
    for (int e = e0 + threadIdx.x; e < e1; e += 256) {
        int d = dst[e];
        int b = d >> CBSHIFT;
        int r = atomicAdd(&cur[b], 1);
        pairs[base[b] + r] = (unsigned int)src[e] | ((unsigned int)(d & 255) << 17);
    }
}

// ---------------- pass 2: per-bucket sort -> csr_src, row_start, indeg, dinv ----------------
// one block per coarse bucket (~4100 entries, 256 dst nodes)
__global__ __launch_bounds__(256) void k_p2(const unsigned int* __restrict__ pairs,
                                            const int* __restrict__ bstart,
                                            int* __restrict__ csr_src,
                                            int* __restrict__ row_start,
                                            int* __restrict__ indeg,
                                            float* __restrict__ dinv) {
    __shared__ int hist[256], sst[256], cur[256], s[256];
    const int b = blockIdx.x;
    const int t = threadIdx.x;
    const int beg = bstart[b];
    const int end = bstart[b + 1];
    hist[t] = 0; cur[t] = 0;
    __syncthreads();
    for (int i = beg + t; i < end; i += 256)
        atomicAdd(&hist[pairs[i] >> 17], 1);
    __syncthreads();
    int v = hist[t];
    s[t] = v;
    __syncthreads();
    for (int off = 1; off < 256; off <<= 1) {
        int x = (t >= off) ? s[t - off] : 0;
        __syncthreads();
        s[t] += x;
        __syncthreads();
    }
    sst[t] = s[t] - v;
    __syncthreads();
    {
        int node = (b << CBSHIFT) + t;
        if (node < N_NODES) {
            row_start[node] = beg + sst[t];
            indeg[node] = v;
            dinv[node] = rsqrtf((float)v + 1.0f);
        }
    }
    for (int i = beg + t; i < end; i += 256) {
        unsigned int pv = pairs[i];
        int dl = pv >> 17;
        int r = atomicAdd(&cur[dl], 1);
        csr_src[beg + sst[dl] + r] = (int)(pv & 0x1FFFFu);
    }
}

// ---------------- degree-sort (descending: heavy blocks dispatch first) ----------------
__global__ __launch_bounds__(256) void k_dhist(const int* __restrict__ indeg,
                                               int* __restrict__ dcount) {
    __shared__ int h[64];
    if (threadIdx.x < 64) h[threadIdx.x] = 0;
    __syncthreads();
    const int i0 = blockIdx.x * DP_NPB;
    const int i1 = min(i0 + DP_NPB, N_NODES);
    for (int i = i0 + threadIdx.x; i < i1; i += 256)
        atomicAdd(&h[63 - min(indeg[i], 63)], 1);
    __syncthreads();
    if (threadIdx.x < 64) {
        int v = h[threadIdx.x];
        if (v) atomicAdd(&dcount[threadIdx.x], v);
    }
}

__global__ __launch_bounds__(64) void k_dscan(const int* __restrict__ dcount,
                                              int* __restrict__ dcur) {
    __shared__ int s[64];
    const int t = threadIdx.x;
    int v = dcount[t];
    s[t] = v;
    __syncthreads();
    for (int off = 1; off < 64; off <<= 1) {
        int x = (t >= off) ? s[t - off] : 0;
        __syncthreads();
        s[t] += x;
        __syncthreads();
    }
    dcur[t] = s[t] - v;
}

__global__ __launch_bounds__(256) void k_dperm(const int* __restrict__ indeg,
                                               int* __restrict__ dcur,
                                               int* __restrict__ perm) {
    __shared__ int h[64], base[64], cur[64];
    if (threadIdx.x < 64) { h[threadIdx.x] = 0; cur[threadIdx.x] = 0; }
    __syncthreads();
    const int i0 = blockIdx.x * DP_NPB;
    const int i1 = min(i0 + DP_NPB, N_NODES);
    for (int i = i0 + threadIdx.x; i < i1; i += 256)
        atomicAdd(&h[63 - min(indeg[i], 63)], 1);
    __syncthreads();
    if (threadIdx.x < 64) {
        int c = h[threadIdx.x];
        base[threadIdx.x] = c ? atomicAdd(&dcur[threadIdx.x], c) : 0;
    }
    __syncthreads();
    for (int i = i0 + threadIdx.x; i < i1; i += 256) {
        int bin = 63 - min(indeg[i], 63);
        int r = atomicAdd(&cur[bin], 1);
        perm[base[bin] + r] = i;
    }
}

// ---------------- W1 prep: fp32 [k][n] -> bf16 transposed [n][k] ----------------
__global__ void k_prepw(const float* __restrict__ W1, unsigned short* __restrict__ WT1) {
    for (int i = threadIdx.x; i < 128 * 128; i += blockDim.x) {
        int n = i >> 7, k = i & 127;
        WT1[i] = f2bf(W1[k * 128 + n]);
    }
}

// ---------------- layer-2 collapse: w2l = W2 @ Wlin, c2 = b2.Wlin + blin ----------------
__global__ void k_prepv(const float* __restrict__ W2, const float* __restrict__ Wlin,
                        const float* __restrict__ b2, const float* __restrict__ blin,
                        float* __restrict__ w2l) {
    int i = threadIdx.x;   // 128 threads
    float s = 0.f;
    for (int j = 0; j < 128; ++j) s += W2[i * 128 + j] * Wlin[j];
    w2l[i] = s;
    if (i == 0) {
        float c = 0.f;
        for (int j = 0; j < 128; ++j) c += b2[j] * Wlin[j];
        w2l[128] = c + blin[0];
    }
}

// ---------------- MFMA GEMM: C[r,:] = bf16( (X[r,:] @ W) * dinv[r] ) ----------------
template<bool SRC_BF16>
__global__ __launch_bounds__(256) void k_gemm_mfma(const void* __restrict__ Xv,
                                                   const unsigned short* __restrict__ WT,
                                                   const float* __restrict__ dinv,
                                                   unsigned short* __restrict__ C,
                                                   int nrows) {
    __shared__ unsigned short As[128][136];
    __shared__ unsigned short Ws[128][136];
    const int tid = threadIdx.x;
    const int R0 = blockIdx.x * 128;

    {
        int r = tid >> 1;
        int h = (tid & 1) * 64;
        int gr = R0 + r;
        if (SRC_BF16) {
            const unsigned short* X = (const unsigned short*)Xv;
            for (int c = 0; c < 64; c += 8) {
                short8 v = {};
                if (gr < nrows) v = *(const short8*)(X + (size_t)gr * NFEAT + h + c);
                *(short8*)(&As[r][h + c]) = v;
            }
        } else {
            const float* X = (const float*)Xv;
            for (int c = 0; c < 64; c += 8) {
                short8 v = {};
                if (gr < nrows) {
                    float4 f0 = *(const float4*)(X + (size_t)gr * NFEAT + h + c);
                    float4 f1 = *(const float4*)(X + (size_t)gr * NFEAT + h + c + 4);
                    v[0] = (short)f2bf(f0.x); v[1] = (short)f2bf(f0.y);
                    v[2] = (short)f2bf(f0.z); v[3] = (short)f2bf(f0.w);
                    v[4] = (short)f2bf(f1.x); v[5] = (short)f2bf(f1.y);
                    v[6] = (short)f2bf(f1.z); v[7] = (short)f2bf(f1.w);
                }
                *(short8*)(&As[r][h + c]) = v;
            }
        }
    }
    {
        int n = tid >> 1;
        int h = (tid & 1) * 64;
        for (int c = 0; c < 64; c += 8)
            *(short8*)(&Ws[n][h + c]) = *(const short8*)(WT + n * 128 + h + c);
    }
    __syncthreads();

    const int wv   = tid >> 6;
    const int lane = tid & 63;
    const int m16  = lane & 15;
    const int quad = lane >> 4;

    f32x4 acc[2][8] = {};
    #pragma unroll
    for (int ks = 0; ks < 4; ++ks) {
        const int k0 = ks * 32 + quad * 8;
        short8 a0 = *(const short8*)(&As[wv * 32 + m16][k0]);
        short8 a1 = *(const short8*)(&As[wv * 32 + 16 + m16][k0]);
        short8 bb[8];
        #pragma unroll
        for (int ct = 0; ct < 8; ++ct)
            bb[ct] = *(const short8*)(&Ws[ct * 16 + m16][k0]);
        #pragma unroll
        for (int ct = 0; ct < 8; ++ct) {
            acc[0][ct] = __builtin_amdgcn_mfma_f32_16x16x32_bf16(a0, bb[ct], acc[0][ct], 0, 0, 0);
            acc[1][ct] = __builtin_amdgcn_mfma_f32_16x16x32_bf16(a1, bb[ct], acc[1][ct], 0, 0, 0);
        }
    }

    #pragma unroll
    for (int t = 0; t < 2; ++t) {
        int rbase = R0 + wv * 32 + t * 16 + quad * 4;
        #pragma unroll
        for (int reg = 0; reg < 4; ++reg) {
            int gr = rbase + reg;
            if (gr < nrows) {
                float dv = dinv[gr];
                #pragma unroll
                for (int ct = 0; ct < 8; ++ct)
                    C[(size_t)gr * NFEAT + ct * 16 + m16] = f2bf(acc[t][ct][reg] * dv);
            }
        }
    }
}

// ---------------- gather core: reg-broadcast idx, 8-deep row MLP ----------------
// group (16 lanes) owns one node; lane p covers features p*8..p*8+7.
// Returns acc[8]; assumes cnt>=0. Indices for edges <64 preloaded to i0..i3.
#define GATHER_BODY(tab)                                                      \
    float acc[8] = {};                                                        \
    acc8(acc, tab[(size_t)node * 16 + p]);  /* self loop */                   \
    int i0 = 0, i1 = 0, i2 = 0, i3 = 0;                                       \
    if (p < cnt)      i0 = csr_src[beg + p];                                  \
    if (16 + p < cnt) i1 = csr_src[beg + 16 + p];                             \
    if (32 + p < cnt) i2 = csr_src[beg + 32 + p];                             \
    if (48 + p < cnt) i3 = csr_src[beg + 48 + p];                             \
    int j = 0;                                                                \
    _Pragma("unroll 1")                                                       \
    while (j < cnt) {                                                         \
        uint4 v[8];                                                           \
        if (j < 64) {                                                         \
            int r = j >> 4;                                                   \
            int cur = (r == 0) ? i0 : ((r == 1) ? i1 : ((r == 2) ? i2 : i3)); \
            int slb = (lane & 48) | (j & 15);                                 \
            _Pragma("unroll")                                                 \
            for (int q = 0; q < 8; ++q) {                                     \
                int idx = __shfl(cur, slb + q);                               \
                if (j + q >= cnt) idx = node;                                 \
                v[q] = tab[(size_t)idx * 16 + p];                             \
            }                                                                 \
        } else {                                                              \
            _Pragma("unroll")                                                 \
            for (int q = 0; q < 8; ++q) {                                     \
                int idx = (j + q < cnt) ? csr_src[beg + j + q] : node;        \
                v[q] = tab[(size_t)idx * 16 + p];                             \
            }                                                                 \
        }                                                                     \
        _Pragma("unroll")                                                     \
        for (int q = 0; q < 8; ++q) if (j + q < cnt) acc8(acc, v[q]);         \
        j += 8;                                                               \
    }

// ---------------- gather layer 1 -> bf16( relu(dv*sum + b1) * dv ) ----------------
__global__ __launch_bounds__(256) void k_gather1(const unsigned short* __restrict__ xwb,
                                                 const int* __restrict__ csr_src,
                                                 const int* __restrict__ row_start,
                                                 const int* __restrict__ indeg,
                                                 const float* __restrict__ dinv,
                                                 const float* __restrict__ b,
                                                 const int* __restrict__ perm,
                                                 uint4* __restrict__ outb) {
    long long t = (long long)blockIdx.x * blockDim.x + threadIdx.x;
    int wid = (int)(t >> 6);
    const int lane = threadIdx.x & 63;
    const int g = lane >> 4;
    const int p = lane & 15;
    int nidx = wid * 4 + g;
    if (nidx >= N_NODES) return;
    int node = perm[nidx];
    const uint4* tab = (const uint4*)xwb;
    const int beg = row_start[node];
    const int cnt = indeg[node];
    GATHER_BODY(tab)
    float dv = dinv[node];
    float4 b0 = *(const float4*)(b + p * 8);
    float4 b1 = *(const float4*)(b + p * 8 + 4);
    float r0 = fmaxf(acc[0] * dv + b0.x, 0.f) * dv;
    float r1 = fmaxf(acc[1] * dv + b0.y, 0.f) * dv;
    float r2 = fmaxf(acc[2] * dv + b0.z, 0.f) * dv;
    float r3 = fmaxf(acc[3] * dv + b0.w, 0.f) * dv;
    float r4 = fmaxf(acc[4] * dv + b1.x, 0.f) * dv;
    float r5 = fmaxf(acc[5] * dv + b1.y, 0.f) * dv;
    float r6 = fmaxf(acc[6] * dv + b1.z, 0.f) * dv;
    float r7 = fmaxf(acc[7] * dv + b1.w, 0.f) * dv;
    uint4 o;
    o.x = (unsigned int)f2bf(r0) | ((unsigned int)f2bf(r1) << 16);
    o.y = (unsigned int)f2bf(r2) | ((unsigned int)f2bf(r3) << 16);
    o.z = (unsigned int)f2bf(r4) | ((unsigned int)f2bf(r5) << 16);
    o.w = (unsigned int)f2bf(r6) | ((unsigned int)f2bf(r7) << 16);
    outb[(size_t)node * 16 + p] = o;
}

// ---------------- gather layer 2 (on h1s) + dot w2l + graph segment-sum ----------------
__global__ __launch_bounds__(256) void k_gather2_pool(const unsigned short* __restrict__ h1s,
                                                      const int* __restrict__ csr_src,
                                                      const int* __restrict__ row_start,
                                                      const int* __restrict__ indeg,
                                                      const float* __restrict__ dinv,
                                                      const float* __restrict__ w2l,
                                                      const int* __restrict__ perm,
                                                      const int* __restrict__ batch,
                                                      float* __restrict__ gsum) {
    long long t = (long long)blockIdx.x * blockDim.x + threadIdx.x;
    int wid = (int)(t >> 6);
    const int lane = threadIdx.x & 63;
    const int g = lane >> 4;
    const int p = lane & 15;
    int nidx = wid * 4 + g;
    if (nidx >= N_NODES) return;
    int node = perm[nidx];
    const uint4* tab = (const uint4*)h1s;
    const int beg = row_start[node];
    const int cnt = indeg[node];
    GATHER_BODY(tab)
    float dv = dinv[node];
    float4 w0 = *(const float4*)(w2l + p * 8);
    float4 w1 = *(const float4*)(w2l + p * 8 + 4);
    float s = acc[0] * w0.x + acc[1] * w0.y + acc[2] * w0.z + acc[3] * w0.w
            + acc[4] * w1.x + acc[5] * w1.y + acc[6] * w1.z + acc[7] * w1.w;
    s += __shfl_xor(s, 1);
    s += __shfl_xor(s, 2);
    s += __shfl_xor(s, 4);
    s += __shfl_xor(s, 8);
    if (p == 0) atomicAdd(&gsum[batch[node]], s * dv);
}

// ---------------- final: counts via binary search on sorted batch; +c2 ----------------
__global__ void k_final(const float* __restrict__ gsum, const int* __restrict__ batch,
                        const float* __restrict__ c2, float* __restrict__ out) {
    int g = blockIdx.x * blockDim.x + threadIdx.x;
    if (g >= NGRAPHS) return;
    int lo = 0, hi = N_NODES;
    while (lo < hi) { int m = (lo + hi) >> 1; if (batch[m] < g) lo = m + 1; else hi = m; }
    int lb = lo;
    lo = 0; hi = N_NODES;
    int g1 = g + 1;
    while (lo < hi) { int m = (lo + hi) >> 1; if (batch[m] < g1) lo = m + 1; else hi = m; }
    float cnt = (float)(lo - lb);
    out[g] = gsum[g] / fmaxf(cnt, 1.0f) + c2[0];
}

extern "C" void kernel_launch(void* const* d_in, const int* in_sizes, int n_in,
                              void* d_out, int out_size, void* d_ws, size_t ws_size,
                              hipStream_t stream) {
    const float* x    = (const float*)d_in[0];
    const int*   ei   = (const int*)d_in[1];
    const int*   bat  = (const int*)d_in[2];
    const float* W1   = (const float*)d_in[3];
    const float* b1   = (const float*)d_in[4];
    const float* W2   = (const float*)d_in[5];
    const float* b2   = (const float*)d_in[6];
    const float* Wlin = (const float*)d_in[7];
    const float* blin = (const float*)d_in[8];
    float* out = (float*)d_out;

    const int* src = ei;
    const int* dst = ei + N_EDGES;

    // ---- workspace layout ----
    const size_t NF = (size_t)N_NODES * NFEAT;
    unsigned short* bufA = (unsigned short*)d_ws;          // bf16 xw1 table (dinv-scaled)
    unsigned short* bufB = bufA + NF;                      // bf16 h1s table
    float* dinv    = (float*)(bufB + NF);                  // [N]
    int* row_start = (int*)(dinv + N_NODES);               // [N]
    int* indeg     = row_start + N_NODES;                  // [N]
    int* perm      = indeg + N_NODES;                      // [N]
    int* bstart    = perm + N_NODES;                       // [NCB+1]
    int* gcur      = bstart + NCB + 1;                     // [NCB]
    int* bcount    = gcur + NCB;                           // [NCB]   } zeroed
    float* gsum    = (float*)(bcount + NCB);               // [G]     }
    int* dcount    = (int*)(gsum + NGRAPHS);               // [64]    }
    int* dcur      = dcount + 64;                          // [64]    }
    unsigned short* WT1 = (unsigned short*)(dcur + 64);    // [16384]
    float* w2l     = (float*)(WT1 + 128 * 128);            // [132] (c2 at [128])
    unsigned int* pairs = (unsigned int*)(w2l + 132);      // [E]
    int* csr_src   = (int*)(pairs + N_EDGES);              // [E]

    const int BS = 256;
    int gemm_blocks = (N_NODES + 127) / 128;
    int p1_blocks   = (N_EDGES + P1_EPB - 1) / P1_EPB;     // 782
    int nwaves      = (N_NODES + 3) / 4;                   // 4 nodes per wave
    int g_blocks    = (int)(((long long)nwaves * 64 + BS - 1) / BS);

    // ---- zero accumulators (bcount,gsum,dcount,dcur contiguous) ----
    hipMemsetAsync(bcount, 0, (NCB + 128) * sizeof(int) + NGRAPHS * sizeof(float), stream);

    // ---- two-level counting sort -> CSR (+ indeg, dinv, row_start) ----
    k_bhist<<<256, BS, 0, stream>>>(dst, bcount);
    k_bscan<<<1, BS, 0, stream>>>(bcount, bstart, gcur);
    k_p1<<<p1_blocks, BS, 0, stream>>>(src, dst, gcur, pairs);
    k_p2<<<NCB, BS, 0, stream>>>(pairs, bstart, csr_src, row_start, indeg, dinv);

    // ---- degree-sorted permutation (descending: heavy first) ----
    k_dhist<<<DP_BLOCKS, BS, 0, stream>>>(indeg, dcount);
    k_dscan<<<1, 64, 0, stream>>>(dcount, dcur);
    k_dperm<<<DP_BLOCKS, BS, 0, stream>>>(indeg, dcur, perm);

    // ---- weight prep ----
    k_prepw<<<1, BS, 0, stream>>>(W1, WT1);
    k_prepv<<<1, 128, 0, stream>>>(W2, Wlin, b2, blin, w2l);

    // ---- layer 1 ----
    k_gemm_mfma<false><<<gemm_blocks, BS, 0, stream>>>(x, WT1, dinv, bufA, N_NODES);
    k_gather1<<<g_blocks, BS, 0, stream>>>(bufA, csr_src, row_start, indeg, dinv, b1, perm,
                                           (uint4*)bufB);

    // ---- layer 2 + pool + linear (GEMM2 collapsed into w2l) ----
    k_gather2_pool<<<g_blocks, BS, 0, stream>>>(bufB, csr_src, row_start, indeg, dinv, w2l,
                                                perm, bat, gsum);

    // ---- final ----
    k_final<<<(NGRAPHS + BS - 1) / BS, BS, 0, stream>>>(gsum, bat, w2l + 128, out);
}

// Round 10
// 323.957 us; speedup vs baseline: 1.1192x; 1.1192x over previous
//
#include <hip/hip_runtime.h>

#define N_NODES   100000
#define N_EDGES   1600000
#define NFEAT     128
#define NGRAPHS   2048
#define CBSHIFT   8                        // 256 nodes per coarse bucket
#define NCB       ((N_NODES + 255) / 256)  // 391
#define P1_EPB    2048                     // edges per k_p1 block
#define DP_BLOCKS 25
#define DP_NPB    ((N_NODES + DP_BLOCKS - 1) / DP_BLOCKS)   // 4000 nodes/block

typedef __attribute__((ext_vector_type(8))) short short8;   // 8 bf16 = 4 VGPRs
typedef __attribute__((ext_vector_type(4))) float f32x4;

// RNE float -> bf16 (finite inputs)
__device__ __forceinline__ unsigned short f2bf(float f) {
    unsigned int u = __float_as_uint(f);
    u += 0x7FFFu + ((u >> 16) & 1u);
    return (unsigned short)(u >> 16);
}

// accumulate 8 bf16 (packed in uint4) into 8 fp32
__device__ __forceinline__ void acc8(float* acc, uint4 v) {
    acc[0] += __uint_as_float(v.x << 16);
    acc[1] += __uint_as_float(v.x & 0xFFFF0000u);
    acc[2] += __uint_as_float(v.y << 16);
    acc[3] += __uint_as_float(v.y & 0xFFFF0000u);
    acc[4] += __uint_as_float(v.z << 16);
    acc[5] += __uint_as_float(v.z & 0xFFFF0000u);
    acc[6] += __uint_as_float(v.w << 16);
    acc[7] += __uint_as_float(v.w & 0xFFFF0000u);
}

// ---------------- coarse bucket histogram (LDS-aggregated) ----------------
__global__ __launch_bounds__(256) void k_bhist(const int* __restrict__ dst,
                                               int* __restrict__ bcount) {
    __shared__ int h[NCB];
    for (int i = threadIdx.x; i < NCB; i += 256) h[i] = 0;
    __syncthreads();
    int stride = gridDim.x * 256;
    for (int e = blockIdx.x * 256 + threadIdx.x; e < N_EDGES; e += stride)
        atomicAdd(&h[dst[e] >> CBSHIFT], 1);
    __syncthreads();
    for (int i = threadIdx.x; i < NCB; i += 256) {
        int v = h[i];
        if (v) atomicAdd(&bcount[i], v);
    }
}

// ---------------- scan of 391 bucket counts -> bstart, gcur ----------------
__global__ __launch_bounds__(256) void k_bscan(const int* __restrict__ bcount,
                                               int* __restrict__ bstart,
                                               int* __restrict__ gcur) {
    __shared__ int s[256];
    const int t = threadIdx.x;
    int v0 = (2 * t < NCB) ? bcount[2 * t] : 0;
    int v1 = (2 * t + 1 < NCB) ? bcount[2 * t + 1] : 0;
    int local = v0 + v1;
    s[t] = local;
    __syncthreads();
    for (int off = 1; off < 256; off <<= 1) {
        int x = (t >= off) ? s[t - off] : 0;
        __syncthreads();
        s[t] += x;
        __syncthreads();
    }
    int excl = s[t] - local;
    if (2 * t < NCB)     { bstart[2 * t] = excl;          gcur[2 * t] = excl; }
    if (2 * t + 1 < NCB) { bstart[2 * t + 1] = excl + v0; gcur[2 * t + 1] = excl + v0; }
    if (t == 255) bstart[NCB] = s[255];
}

// ---------------- pass 1: block-ranked scatter into coarse bucket regions ----------------
// pairs[pos] = src | (dlocal << 17), dlocal in [0,256)
__global__ __launch_bounds__(256) void k_p1(const int* __restrict__ src,
                                            const int* __restrict__ dst,
                                            int* __restrict__ gcur,
                                            unsigned int* __restrict__ pairs) {
    __shared__ int hist[NCB], base[NCB], cur[NCB];
    for (int i = threadIdx.x; i < NCB; i += 256) { hist[i] = 0; cur[i] = 0; }
    __syncthreads();
    const int e0 = blockIdx.x * P1_EPB;
    const int e1 = min(e0 + P1_EPB, N_EDGES);
    for (int e = e0 + threadIdx.x; e < e1; e += 256)
        atomicAdd(&hist[dst[e] >> CBSHIFT], 1);
    __syncthreads();
    for (int i = threadIdx.x; i < NCB; i += 256) {
        int c = hist[i];
        base[i] = c ? atomicAdd(&gcur[i], c) : 0;
    }
    __syncthreads();
    for (int e = e0 + threadIdx.x; e < e1; e += 256) {
        int d = dst[e];
        int b = d >> CBSHIFT;
        int r = atomicAdd(&cur[b], 1);
        pairs[base[b] + r] = (unsigned int)src[e] | ((unsigned int)(d & 255) << 17);
    }
}

// ---------------- pass 2: per-bucket sort -> csr_src, row_start, indeg, dinv ----------------
__global__ __launch_bounds__(256) void k_p2(const unsigned int* __restrict__ pairs,
                                            const int* __restrict__ bstart,
                                            int* __restrict__ csr_src,
                                            int* __restrict__ row_start,
                                            int* __restrict__ indeg,
                                            float* __restrict__ dinv) {
    __shared__ int hist[256], sst[256], cur[256], s[256];
    const int b = blockIdx.x;
    const int t = threadIdx.x;
    const int beg = bstart[b];
    const int end = bstart[b + 1];
    hist[t] = 0; cur[t] = 0;
    __syncthreads();
    for (int i = beg + t; i < end; i += 256)
        atomicAdd(&hist[pairs[i] >> 17], 1);
    __syncthreads();
    int v = hist[t];
    s[t] = v;
    __syncthreads();
    for (int off = 1; off < 256; off <<= 1) {
        int x = (t >= off) ? s[t - off] : 0;
        __syncthreads();
        s[t] += x;
        __syncthreads();
    }
    sst[t] = s[t] - v;
    __syncthreads();
    {
        int node = (b << CBSHIFT) + t;
        if (node < N_NODES) {
            row_start[node] = beg + sst[t];
            indeg[node] = v;
            dinv[node] = rsqrtf((float)v + 1.0f);
        }
    }
    for (int i = beg + t; i < end; i += 256) {
        unsigned int pv = pairs[i];
        int dl = pv >> 17;
        int r = atomicAdd(&cur[dl], 1);
        csr_src[beg + sst[dl] + r] = (int)(pv & 0x1FFFFu);
    }
}

// ---------------- degree-sort (descending: heavy blocks dispatch first) ----------------
__global__ __launch_bounds__(256) void k_dhist(const int* __restrict__ indeg,
                                               int* __restrict__ dcount) {
    __shared__ int h[64];
    if (threadIdx.x < 64) h[threadIdx.x] = 0;
    __syncthreads();
    const int i0 = blockIdx.x * DP_NPB;
    const int i1 = min(i0 + DP_NPB, N_NODES);
    for (int i = i0 + threadIdx.x; i < i1; i += 256)
        atomicAdd(&h[63 - min(indeg[i], 63)], 1);
    __syncthreads();
    if (threadIdx.x < 64) {
        int v = h[threadIdx.x];
        if (v) atomicAdd(&dcount[threadIdx.x], v);
    }
}

__global__ __launch_bounds__(64) void k_dscan(const int* __restrict__ dcount,
                                              int* __restrict__ dcur) {
    __shared__ int s[64];
    const int t = threadIdx.x;
    int v = dcount[t];
    s[t] = v;
    __syncthreads();
    for (int off = 1; off < 64; off <<= 1) {
        int x = (t >= off) ? s[t - off] : 0;
        __syncthreads();
        s[t] += x;
        __syncthreads();
    }
    dcur[t] = s[t] - v;
}

__global__ __launch_bounds__(256) void k_dperm(const int* __restrict__ indeg,
                                               int* __restrict__ dcur,
                                               int* __restrict__ perm) {
    __shared__ int h[64], base[64], cur[64];
    if (threadIdx.x < 64) { h[threadIdx.x] = 0; cur[threadIdx.x] = 0; }
    __syncthreads();
    const int i0 = blockIdx.x * DP_NPB;
    const int i1 = min(i0 + DP_NPB, N_NODES);
    for (int i = i0 + threadIdx.x; i < i1; i += 256)
        atomicAdd(&h[63 - min(indeg[i], 63)], 1);
    __syncthreads();
    if (threadIdx.x < 64) {
        int c = h[threadIdx.x];
        base[threadIdx.x] = c ? atomicAdd(&dcur[threadIdx.x], c) : 0;
    }
    __syncthreads();
    for (int i = i0 + threadIdx.x; i < i1; i += 256) {
        int bin = 63 - min(indeg[i], 63);
        int r = atomicAdd(&cur[bin], 1);
        perm[base[bin] + r] = i;
    }
}

// ---------------- W1 prep: fp32 [k][n] -> bf16 transposed [n][k] ----------------
__global__ void k_prepw(const float* __restrict__ W1, unsigned short* __restrict__ WT1) {
    for (int i = threadIdx.x; i < 128 * 128; i += blockDim.x) {
        int n = i >> 7, k = i & 127;
        WT1[i] = f2bf(W1[k * 128 + n]);
    }
}

// ---------------- layer-2 collapse: w2l = W2 @ Wlin, c2 = b2.Wlin + blin ----------------
__global__ void k_prepv(const float* __restrict__ W2, const float* __restrict__ Wlin,
                        const float* __restrict__ b2, const float* __restrict__ blin,
                        float* __restrict__ w2l) {
    int i = threadIdx.x;   // 128 threads
    float s = 0.f;
    for (int j = 0; j < 128; ++j) s += W2[i * 128 + j] * Wlin[j];
    w2l[i] = s;
    if (i == 0) {
        float c = 0.f;
        for (int j = 0; j < 128; ++j) c += b2[j] * Wlin[j];
        w2l[128] = c + blin[0];
    }
}

// ---------------- MFMA GEMM: C[r,:] = bf16( (X[r,:] @ W) * dinv[r] ) ----------------
__global__ __launch_bounds__(256) void k_gemm_mfma(const float* __restrict__ X,
                                                   const unsigned short* __restrict__ WT,
                                                   const float* __restrict__ dinv,
                                                   unsigned short* __restrict__ C,
                                                   int nrows) {
    __shared__ unsigned short As[128][136];
    __shared__ unsigned short Ws[128][136];
    const int tid = threadIdx.x;
    const int R0 = blockIdx.x * 128;

    {
        int r = tid >> 1;
        int h = (tid & 1) * 64;
        int gr = R0 + r;
        for (int c = 0; c < 64; c += 8) {
            short8 v = {};
            if (gr < nrows) {
                float4 f0 = *(const float4*)(X + (size_t)gr * NFEAT + h + c);
                float4 f1 = *(const float4*)(X + (size_t)gr * NFEAT + h + c + 4);
                v[0] = (short)f2bf(f0.x); v[1] = (short)f2bf(f0.y);
                v[2] = (short)f2bf(f0.z); v[3] = (short)f2bf(f0.w);
                v[4] = (short)f2bf(f1.x); v[5] = (short)f2bf(f1.y);
                v[6] = (short)f2bf(f1.z); v[7] = (short)f2bf(f1.w);
            }
            *(short8*)(&As[r][h + c]) = v;
        }
    }
    {
        int n = tid >> 1;
        int h = (tid & 1) * 64;
        for (int c = 0; c < 64; c += 8)
            *(short8*)(&Ws[n][h + c]) = *(const short8*)(WT + n * 128 + h + c);
    }
    __syncthreads();

    const int wv   = tid >> 6;
    const int lane = tid & 63;
    const int m16  = lane & 15;
    const int quad = lane >> 4;

    f32x4 acc[2][8] = {};
    #pragma unroll
    for (int ks = 0; ks < 4; ++ks) {
        const int k0 = ks * 32 + quad * 8;
        short8 a0 = *(const short8*)(&As[wv * 32 + m16][k0]);
        short8 a1 = *(const short8*)(&As[wv * 32 + 16 + m16][k0]);
        short8 bb[8];
        #pragma unroll
        for (int ct = 0; ct < 8; ++ct)
            bb[ct] = *(const short8*)(&Ws[ct * 16 + m16][k0]);
        #pragma unroll
        for (int ct = 0; ct < 8; ++ct) {
            acc[0][ct] = __builtin_amdgcn_mfma_f32_16x16x32_bf16(a0, bb[ct], acc[0][ct], 0, 0, 0);
            acc[1][ct] = __builtin_amdgcn_mfma_f32_16x16x32_bf16(a1, bb[ct], acc[1][ct], 0, 0, 0);
        }
    }

    #pragma unroll
    for (int t = 0; t < 2; ++t) {
        int rbase = R0 + wv * 32 + t * 16 + quad * 4;
        #pragma unroll
        for (int reg = 0; reg < 4; ++reg) {
            int gr = rbase + reg;
            if (gr < nrows) {
                float dv = dinv[gr];
                #pragma unroll
                for (int ct = 0; ct < 8; ++ct)
                    C[(size_t)gr * NFEAT + ct * 16 + m16] = f2bf(acc[t][ct][reg] * dv);
            }
        }
    }
}

// ---------------- gather layer 1 + fused z = (relu(dv*sum + b1)*dv) . w2l ----------------
// node per 16-lane group; lane p covers features p*8..p*8+7; round-8 direct-load body.
__global__ __launch_bounds__(256) void k_gather1(const unsigned short* __restrict__ xwb,
                                                 const int* __restrict__ csr_src,
                                                 const int* __restrict__ row_start,
                                                 const int* __restrict__ indeg,
                                                 const float* __restrict__ dinv,
                                                 const float* __restrict__ b,
                                                 const float* __restrict__ w2l,
                                                 const int* __restrict__ perm,
                                                 float* __restrict__ z) {
    long long t = (long long)blockIdx.x * blockDim.x + threadIdx.x;
    int wid = (int)(t >> 6);
    const int lane = threadIdx.x & 63;
    const int g = lane >> 4;
    const int p = lane & 15;
    int nidx = wid * 4 + g;
    if (nidx >= N_NODES) return;
    int node = perm[nidx];
    const uint4* tab = (const uint4*)xwb;
    const int beg = row_start[node];
    const int cnt = indeg[node];
    float acc[8] = {};
    acc8(acc, tab[(size_t)node * 16 + p]);     // self loop
    int j = 0;
    #pragma unroll 1
    for (; j + 8 <= cnt; j += 8) {
        int i0 = csr_src[beg + j + 0];
        int i1 = csr_src[beg + j + 1];
        int i2 = csr_src[beg + j + 2];
        int i3 = csr_src[beg + j + 3];
        int i4 = csr_src[beg + j + 4];
        int i5 = csr_src[beg + j + 5];
        int i6 = csr_src[beg + j + 6];
        int i7 = csr_src[beg + j + 7];
        uint4 v0 = tab[(size_t)i0 * 16 + p];
        uint4 v1 = tab[(size_t)i1 * 16 + p];
        uint4 v2 = tab[(size_t)i2 * 16 + p];
        uint4 v3 = tab[(size_t)i3 * 16 + p];
        uint4 v4 = tab[(size_t)i4 * 16 + p];
        uint4 v5 = tab[(size_t)i5 * 16 + p];
        uint4 v6 = tab[(size_t)i6 * 16 + p];
        uint4 v7 = tab[(size_t)i7 * 16 + p];
        acc8(acc, v0); acc8(acc, v1); acc8(acc, v2); acc8(acc, v3);
        acc8(acc, v4); acc8(acc, v5); acc8(acc, v6); acc8(acc, v7);
    }
    #pragma unroll 1
    for (; j < cnt; ++j)
        acc8(acc, tab[(size_t)csr_src[beg + j] * 16 + p]);
    float dv = dinv[node];
    float4 b0 = *(const float4*)(b + p * 8);
    float4 b1 = *(const float4*)(b + p * 8 + 4);
    float4 w0 = *(const float4*)(w2l + p * 8);
    float4 w1 = *(const float4*)(w2l + p * 8 + 4);
    float s = fmaxf(acc[0] * dv + b0.x, 0.f) * w0.x
            + fmaxf(acc[1] * dv + b0.y, 0.f) * w0.y
            + fmaxf(acc[2] * dv + b0.z, 0.f) * w0.z
            + fmaxf(acc[3] * dv + b0.w, 0.f) * w0.w
            + fmaxf(acc[4] * dv + b1.x, 0.f) * w1.x
            + fmaxf(acc[5] * dv + b1.y, 0.f) * w1.y
            + fmaxf(acc[6] * dv + b1.z, 0.f) * w1.z
            + fmaxf(acc[7] * dv + b1.w, 0.f) * w1.w;
    s += __shfl_xor(s, 1);
    s += __shfl_xor(s, 2);
    s += __shfl_xor(s, 4);
    s += __shfl_xor(s, 8);
    if (p == 0) z[node] = s * dv;     // z = (dinv*h1).w2l
}

// ---------------- layer 2 + pool over scalars: gsum[batch[d]] += dv_d*(z_d + sum z_s) ----------------
__global__ __launch_bounds__(256) void k_gather2s(const float* __restrict__ z,
                                                  const int* __restrict__ csr_src,
                                                  const int* __restrict__ row_start,
                                                  const int* __restrict__ indeg,
                                                  const float* __restrict__ dinv,
                                                  const int* __restrict__ perm,
                                                  const int* __restrict__ batch,
                                                  float* __restrict__ gsum) {
    int nidx = blockIdx.x * blockDim.x + threadIdx.x;
    if (nidx >= N_NODES) return;
    int node = perm[nidx];
    const int beg = row_start[node];
    const int cnt = indeg[node];
    float a = z[node];
    int j = 0;
    #pragma unroll 1
    for (; j + 4 <= cnt; j += 4) {
        int i0 = csr_src[beg + j + 0];
        int i1 = csr_src[beg + j + 1];
        int i2 = csr_src[beg + j + 2];
        int i3 = csr_src[beg + j + 3];
        a += z[i0] + z[i1] + z[i2] + z[i3];
    }
    #pragma unroll 1
    for (; j < cnt; ++j)
        a += z[csr_src[beg + j]];
    atomicAdd(&gsum[batch[node]], a * dinv[node]);
}

// ---------------- final: counts via binary search on sorted batch; +c2 ----------------
__global__ void k_final(const float* __restrict__ gsum, const int* __restrict__ batch,
                        const float* __restrict__ c2, float* __restrict__ out) {
    int g = blockIdx.x * blockDim.x + threadIdx.x;
    if (g >= NGRAPHS) return;
    int lo = 0, hi = N_NODES;
    while (lo < hi) { int m = (lo + hi) >> 1; if (batch[m] < g) lo = m + 1; else hi = m; }
    int lb = lo;
    lo = 0; hi = N_NODES;
    int g1 = g + 1;
    while (lo < hi) { int m = (lo + hi) >> 1; if (batch[m] < g1) lo = m + 1; else hi = m; }
    float cnt = (float)(lo - lb);
    out[g] = gsum[g] / fmaxf(cnt, 1.0f) + c2[0];
}

extern "C" void kernel_launch(void* const* d_in, const int* in_sizes, int n_in,
                              void* d_out, int out_size, void* d_ws, size_t ws_size,
                              hipStream_t stream) {
    const float* x    = (const float*)d_in[0];
    const int*   ei   = (const int*)d_in[1];
    const int*   bat  = (const int*)d_in[2];
    const float* W1   = (const float*)d_in[3];
    const float* b1   = (const float*)d_in[4];
    const float* W2   = (const float*)d_in[5];
    const float* b2   = (const float*)d_in[6];
    const float* Wlin = (const float*)d_in[7];
    const float* blin = (const float*)d_in[8];
    float* out = (float*)d_out;

    const int* src = ei;
    const int* dst = ei + N_EDGES;

    // ---- workspace layout ----
    const size_t NF = (size_t)N_NODES * NFEAT;
    unsigned short* bufA = (unsigned short*)d_ws;          // bf16 xw1 table (dinv-scaled)
    float* z       = (float*)(bufA + NF);                  // [N] scalar layer-2 inputs
    float* dinv    = z + N_NODES;                          // [N]
    int* row_start = (int*)(dinv + N_NODES);               // [N]
    int* indeg     = row_start + N_NODES;                  // [N]
    int* perm      = indeg + N_NODES;                      // [N]
    int* bstart    = perm + N_NODES;                       // [NCB+1]
    int* gcur      = bstart + NCB + 1;                     // [NCB]
    int* bcount    = gcur + NCB;                           // [NCB]   } zeroed
    float* gsum    = (float*)(bcount + NCB);               // [G]     }
    int* dcount    = (int*)(gsum + NGRAPHS);               // [64]    }
    int* dcur      = dcount + 64;                          // [64]    }
    unsigned short* WT1 = (unsigned short*)(dcur + 64);    // [16384]
    float* w2l     = (float*)(WT1 + 128 * 128);            // [132] (c2 at [128])
    unsigned int* pairs = (unsigned int*)(w2l + 132);      // [E]
    int* csr_src   = (int*)(pairs + N_EDGES);              // [E]

    const int BS = 256;
    int gemm_blocks = (N_NODES + 127) / 128;
    int p1_blocks   = (N_EDGES + P1_EPB - 1) / P1_EPB;     // 782
    int nwaves      = (N_NODES + 3) / 4;                   // 4 nodes per wave
    int g_blocks    = (int)(((long long)nwaves * 64 + BS - 1) / BS);
    int node_blocks = (N_NODES + BS - 1) / BS;

    // ---- zero accumulators (bcount,gsum,dcount,dcur contiguous) ----
    hipMemsetAsync(bcount, 0, (NCB + 128) * sizeof(int) + NGRAPHS * sizeof(float), stream);

    // ---- two-level counting sort -> CSR (+ indeg, dinv, row_start) ----
    k_bhist<<<256, BS, 0, stream>>>(dst, bcount);
    k_bscan<<<1, BS, 0, stream>>>(bcount, bstart, gcur);
    k_p1<<<p1_blocks, BS, 0, stream>>>(src, dst, gcur, pairs);
    k_p2<<<NCB, BS, 0, stream>>>(pairs, bstart, csr_src, row_start, indeg, dinv);

    // ---- degree-sorted permutation (descending: heavy first) ----
    k_dhist<<<DP_BLOCKS, BS, 0, stream>>>(indeg, dcount);
    k_dscan<<<1, 64, 0, stream>>>(dcount, dcur);
    k_dperm<<<DP_BLOCKS, BS, 0, stream>>>(indeg, dcur, perm);

    // ---- weight prep ----
    k_prepw<<<1, BS, 0, stream>>>(W1, WT1);
    k_prepv<<<1, 128, 0, stream>>>(W2, Wlin, b2, blin, w2l);

    // ---- layer 1 (GEMM + gather with fused layer-2 projection to scalar z) ----
    k_gemm_mfma<<<gemm_blocks, BS, 0, stream>>>(x, WT1, dinv, bufA, N_NODES);
    k_gather1<<<g_blocks, BS, 0, stream>>>(bufA, csr_src, row_start, indeg, dinv, b1, w2l,
                                           perm, z);

    // ---- layer 2 + pool over scalar z ----
    k_gather2s<<<node_blocks, BS, 0, stream>>>(z, csr_src, row_start, indeg, dinv, perm,
                                               bat, gsum);

    // ---- final ----
    k_final<<<(NGRAPHS + BS - 1) / BS, BS, 0, stream>>>(gsum, bat, w2l + 128, out);
}

// Round 11
// 299.587 us; speedup vs baseline: 1.2102x; 1.0813x over previous
//
#include <hip/hip_runtime.h>

#define N_NODES   100000
#define N_EDGES   1600000
#define NFEAT     128
#define NGRAPHS   2048
#define CBSHIFT   8                        // 256 nodes per coarse bucket
#define NCB       ((N_NODES + 255) / 256)  // 391
#define P1_EPB    8192                     // edges per k_p1 block
#define DP_BLOCKS 25
#define DP_NPB    ((N_NODES + DP_BLOCKS - 1) / DP_BLOCKS)   // 4000 nodes/block

typedef __attribute__((ext_vector_type(8))) short short8;   // 8 bf16 = 4 VGPRs
typedef __attribute__((ext_vector_type(4))) float f32x4;

// RNE float -> bf16 (finite inputs)
__device__ __forceinline__ unsigned short f2bf(float f) {
    unsigned int u = __float_as_uint(f);
    u += 0x7FFFu + ((u >> 16) & 1u);
    return (unsigned short)(u >> 16);
}

// accumulate 8 bf16 (packed in uint4) into 8 fp32
__device__ __forceinline__ void acc8(float* acc, uint4 v) {
    acc[0] += __uint_as_float(v.x << 16);
    acc[1] += __uint_as_float(v.x & 0xFFFF0000u);
    acc[2] += __uint_as_float(v.y << 16);
    acc[3] += __uint_as_float(v.y & 0xFFFF0000u);
    acc[4] += __uint_as_float(v.z << 16);
    acc[5] += __uint_as_float(v.z & 0xFFFF0000u);
    acc[6] += __uint_as_float(v.w << 16);
    acc[7] += __uint_as_float(v.w & 0xFFFF0000u);
}

// ---------------- coarse bucket histogram (LDS-aggregated) ----------------
__global__ __launch_bounds__(256) void k_bhist(const int* __restrict__ dst,
                                               int* __restrict__ bcount) {
    __shared__ int h[NCB];
    for (int i = threadIdx.x; i < NCB; i += 256) h[i] = 0;
    __syncthreads();
    int stride = gridDim.x * 256;
    for (int e = blockIdx.x * 256 + threadIdx.x; e < N_EDGES; e += stride)
        atomicAdd(&h[dst[e] >> CBSHIFT], 1);
    __syncthreads();
    for (int i = threadIdx.x; i < NCB; i += 256) {
        int v = h[i];
        if (v) atomicAdd(&bcount[i], v);
    }
}

// ---------------- multi-role: block 0 = bucket scan; 1-16 = W1 prep; 17 = w2l; 18+ = zero ----------------
__global__ __launch_bounds__(256) void k_misc(const int* __restrict__ bcount,
                                              int* __restrict__ bstart,
                                              int* __restrict__ gcur,
                                              const float* __restrict__ W1,
                                              unsigned short* __restrict__ WT1,
                                              const float* __restrict__ W2,
                                              const float* __restrict__ Wlin,
                                              const float* __restrict__ b2,
                                              const float* __restrict__ blin,
                                              float* __restrict__ w2l,
                                              int* __restrict__ zeros) {
    const int blk = blockIdx.x;
    const int t = threadIdx.x;
    if (blk == 0) {
        // exclusive scan of NCB bucket counts
        __shared__ int s[256];
        int v0 = (2 * t < NCB) ? bcount[2 * t] : 0;
        int v1 = (2 * t + 1 < NCB) ? bcount[2 * t + 1] : 0;
        int local = v0 + v1;
        s[t] = local;
        __syncthreads();
        for (int off = 1; off < 256; off <<= 1) {
            int x = (t >= off) ? s[t - off] : 0;
            __syncthreads();
            s[t] += x;
            __syncthreads();
        }
        int excl = s[t] - local;
        if (2 * t < NCB)     { bstart[2 * t] = excl;          gcur[2 * t] = excl; }
        if (2 * t + 1 < NCB) { bstart[2 * t + 1] = excl + v0; gcur[2 * t + 1] = excl + v0; }
        if (t == 255) bstart[NCB] = s[255];
    } else if (blk <= 16) {
        // W1 fp32 [k][n] -> bf16 transposed [n][k], 1024 elements/block
        int base = (blk - 1) * 1024 + t * 4;
        #pragma unroll
        for (int q = 0; q < 4; ++q) {
            int i = base + q;
            int n = i >> 7, k = i & 127;
            WT1[i] = f2bf(W1[k * 128 + n]);
        }
    } else if (blk == 17) {
        // w2l = W2 @ Wlin, c2 = b2.Wlin + blin
        if (t < 128) {
            float s = 0.f;
            for (int j = 0; j < 128; ++j) s += W2[t * 128 + j] * Wlin[j];
            w2l[t] = s;
            if (t == 0) {
                float c = 0.f;
                for (int j = 0; j < 128; ++j) c += b2[j] * Wlin[j];
                w2l[128] = c + blin[0];
            }
        }
    } else {
        // zero gsum[NGRAPHS] + dcount[64] + dcur[64]
        int i = (blk - 18) * 256 + t;
        if (i < NGRAPHS + 128) zeros[i] = 0;
    }
}

// ---------------- pass 1: block-ranked scatter into coarse bucket regions ----------------
// pairs[pos] = src | (dlocal << 17), dlocal in [0,256)
__global__ __launch_bounds__(256) void k_p1(const int* __restrict__ src,
                                            const int* __restrict__ dst,
                                            int* __restrict__ gcur,
                                            unsigned int* __restrict__ pairs) {
    __shared__ int hist[NCB], base[NCB], cur[NCB];
    for (int i = threadIdx.x; i < NCB; i += 256) { hist[i] = 0; cur[i] = 0; }
    __syncthreads();
    const int e0 = blockIdx.x * P1_EPB;
    const int e1 = min(e0 + P1_EPB, N_EDGES);
    for (int e = e0 + threadIdx.x; e < e1; e += 256)
        atomicAdd(&hist[dst[e] >> CBSHIFT], 1);
    __syncthreads();
    for (int i = threadIdx.x; i < NCB; i += 256) {
        int c = hist[i];
        base[i] = c ? atomicAdd(&gcur[i], c) : 0;
    }
    __syncthreads();
    for (int e = e0 + threadIdx.x; e < e1; e += 256) {
        int d = dst[e];
        int b = d >> CBSHIFT;
        int r = atomicAdd(&cur[b], 1);
        pairs[base[b] + r] = (unsigned int)src[e] | ((unsigned int)(d & 255) << 17);
    }
}

// ---------------- pass 2: per-bucket sort -> csr_src, row_start, indeg, dinv (+deg hist) ----------------
__global__ __launch_bounds__(256) void k_p2(const unsigned int* __restrict__ pairs,
                                            const int* __restrict__ bstart,
                                            int* __restrict__ csr_src,
                                            int* __restrict__ row_start,
                                            int* __restrict__ indeg,
                                            float* __restrict__ dinv,
                                            int* __restrict__ dcount) {
    __shared__ int hist[256], sst[256], cur[256], s[256], dh[64];
    const int b = blockIdx.x;
    const int t = threadIdx.x;
    const int beg = bstart[b];
    const int end = bstart[b + 1];
    hist[t] = 0; cur[t] = 0;
    if (t < 64) dh[t] = 0;
    __syncthreads();
    for (int i = beg + t; i < end; i += 256)
        atomicAdd(&hist[pairs[i] >> 17], 1);
    __syncthreads();
    int v = hist[t];
    s[t] = v;
    __syncthreads();
    for (int off = 1; off < 256; off <<= 1) {
        int x = (t >= off) ? s[t - off] : 0;
        __syncthreads();
        s[t] += x;
        __syncthreads();
    }
    sst[t] = s[t] - v;
    __syncthreads();
    {
        int node = (b << CBSHIFT) + t;
        if (node < N_NODES) {
            row_start[node] = beg + sst[t];
            indeg[node] = v;
            dinv[node] = rsqrtf((float)v + 1.0f);
            atomicAdd(&dh[63 - min(v, 63)], 1);   // fused degree histogram
        }
    }
    for (int i = beg + t; i < end; i += 256) {
        unsigned int pv = pairs[i];
        int dl = pv >> 17;
        int r = atomicAdd(&cur[dl], 1);
        csr_src[beg + sst[dl] + r] = (int)(pv & 0x1FFFFu);
    }
    __syncthreads();
    if (t < 64 && dh[t]) atomicAdd(&dcount[t], dh[t]);
}

// ---------------- degree-sort scan + permutation (descending: heavy first) ----------------
__global__ __launch_bounds__(64) void k_dscan(const int* __restrict__ dcount,
                                              int* __restrict__ dcur) {
    __shared__ int s[64];
    const int t = threadIdx.x;
    int v = dcount[t];
    s[t] = v;
    __syncthreads();
    for (int off = 1; off < 64; off <<= 1) {
        int x = (t >= off) ? s[t - off] : 0;
        __syncthreads();
        s[t] += x;
        __syncthreads();
    }
    dcur[t] = s[t] - v;
}

__global__ __launch_bounds__(256) void k_dperm(const int* __restrict__ indeg,
                                               int* __restrict__ dcur,
                                               int* __restrict__ perm) {
    __shared__ int h[64], base[64], cur[64];
    if (threadIdx.x < 64) { h[threadIdx.x] = 0; cur[threadIdx.x] = 0; }
    __syncthreads();
    const int i0 = blockIdx.x * DP_NPB;
    const int i1 = min(i0 + DP_NPB, N_NODES);
    for (int i = i0 + threadIdx.x; i < i1; i += 256)
        atomicAdd(&h[63 - min(indeg[i], 63)], 1);
    __syncthreads();
    if (threadIdx.x < 64) {
        int c = h[threadIdx.x];
        base[threadIdx.x] = c ? atomicAdd(&dcur[threadIdx.x], c) : 0;
    }
    __syncthreads();
    for (int i = i0 + threadIdx.x; i < i1; i += 256) {
        int bin = 63 - min(indeg[i], 63);
        int r = atomicAdd(&cur[bin], 1);
        perm[base[bin] + r] = i;
    }
}

// ---------------- MFMA GEMM: C[r,:] = bf16( (X[r,:] @ W) * dinv[r] ) ----------------
__global__ __launch_bounds__(256) void k_gemm_mfma(const float* __restrict__ X,
                                                   const unsigned short* __restrict__ WT,
                                                   const float* __restrict__ dinv,
                                                   unsigned short* __restrict__ C,
                                                   int nrows) {
    __shared__ unsigned short As[128][136];
    __shared__ unsigned short Ws[128][136];
    const int tid = threadIdx.x;
    const int R0 = blockIdx.x * 128;

    {
        int r = tid >> 1;
        int h = (tid & 1) * 64;
        int gr = R0 + r;
        for (int c = 0; c < 64; c += 8) {
            short8 v = {};
            if (gr < nrows) {
                float4 f0 = *(const float4*)(X + (size_t)gr * NFEAT + h + c);
                float4 f1 = *(const float4*)(X + (size_t)gr * NFEAT + h + c + 4);
                v[0] = (short)f2bf(f0.x); v[1] = (short)f2bf(f0.y);
                v[2] = (short)f2bf(f0.z); v[3] = (short)f2bf(f0.w);
                v[4] = (short)f2bf(f1.x); v[5] = (short)f2bf(f1.y);
                v[6] = (short)f2bf(f1.z); v[7] = (short)f2bf(f1.w);
            }
            *(short8*)(&As[r][h + c]) = v;
        }
    }
    {
        int n = tid >> 1;
        int h = (tid & 1) * 64;
        for (int c = 0; c < 64; c += 8)
            *(short8*)(&Ws[n][h + c]) = *(const short8*)(WT + n * 128 + h + c);
    }
    __syncthreads();

    const int wv   = tid >> 6;
    const int lane = tid & 63;
    const int m16  = lane & 15;
    const int quad = lane >> 4;

    f32x4 acc[2][8] = {};
    #pragma unroll
    for (int ks = 0; ks < 4; ++ks) {
        const int k0 = ks * 32 + quad * 8;
        short8 a0 = *(const short8*)(&As[wv * 32 + m16][k0]);
        short8 a1 = *(const short8*)(&As[wv * 32 + 16 + m16][k0]);
        short8 bb[8];
        #pragma unroll
        for (int ct = 0; ct < 8; ++ct)
            bb[ct] = *(const short8*)(&Ws[ct * 16 + m16][k0]);
        #pragma unroll
        for (int ct = 0; ct < 8; ++ct) {
            acc[0][ct] = __builtin_amdgcn_mfma_f32_16x16x32_bf16(a0, bb[ct], acc[0][ct], 0, 0, 0);
            acc[1][ct] = __builtin_amdgcn_mfma_f32_16x16x32_bf16(a1, bb[ct], acc[1][ct], 0, 0, 0);
        }
    }

    #pragma unroll
    for (int t = 0; t < 2; ++t) {
        int rbase = R0 + wv * 32 + t * 16 + quad * 4;
        #pragma unroll
        for (int reg = 0; reg < 4; ++reg) {
            int gr = rbase + reg;
            if (gr < nrows) {
                float dv = dinv[gr];
                #pragma unroll
                for (int ct = 0; ct < 8; ++ct)
                    C[(size_t)gr * NFEAT + ct * 16 + m16] = f2bf(acc[t][ct][reg] * dv);
            }
        }
    }
}

// ---------------- gather layer 1 + fused z = (relu(dv*sum + b1)*dv) . w2l ----------------
// node per 16-lane group; lane p covers features p*8..p*8+7; idx prefetch pipeline.
__global__ __launch_bounds__(256) void k_gather1(const unsigned short* __restrict__ xwb,
                                                 const int* __restrict__ csr_src,
                                                 const int* __restrict__ row_start,
                                                 const int* __restrict__ indeg,
                                                 const float* __restrict__ dinv,
                                                 const float* __restrict__ b,
                                                 const float* __restrict__ w2l,
                                                 const int* __restrict__ perm,
                                                 float* __restrict__ z) {
    long long t = (long long)blockIdx.x * blockDim.x + threadIdx.x;
    int wid = (int)(t >> 6);
    const int lane = threadIdx.x & 63;
    const int g = lane >> 4;
    const int p = lane & 15;
    int nidx = wid * 4 + g;
    if (nidx >= N_NODES) return;
    int node = perm[nidx];
    const uint4* tab = (const uint4*)xwb;
    const int beg = row_start[node];
    const int cnt = indeg[node];
    float acc[8] = {};
    acc8(acc, tab[(size_t)node * 16 + p]);     // self loop
    int j = 0;
    if (cnt >= 8) {
        int idx[8];
        #pragma unroll
        for (int q = 0; q < 8; ++q) idx[q] = csr_src[beg + q];
        #pragma unroll 1
        for (; j + 16 <= cnt; j += 8) {
            uint4 v[8];
            #pragma unroll
            for (int q = 0; q < 8; ++q) v[q] = tab[(size_t)idx[q] * 16 + p];
            #pragma unroll
            for (int q = 0; q < 8; ++q) idx[q] = csr_src[beg + j + 8 + q];   // prefetch next batch
            #pragma unroll
            for (int q = 0; q < 8; ++q) acc8(acc, v[q]);
        }
        {   // drain the pending batch
            uint4 v[8];
            #pragma unroll
            for (int q = 0; q < 8; ++q) v[q] = tab[(size_t)idx[q] * 16 + p];
            #pragma unroll
            for (int q = 0; q < 8; ++q) acc8(acc, v[q]);
            j += 8;
        }
    }
    #pragma unroll 1
    for (; j < cnt; ++j)
        acc8(acc, tab[(size_t)csr_src[beg + j] * 16 + p]);
    float dv = dinv[node];
    float4 b0 = *(const float4*)(b + p * 8);
    float4 b1 = *(const float4*)(b + p * 8 + 4);
    float4 w0 = *(const float4*)(w2l + p * 8);
    float4 w1 = *(const float4*)(w2l + p * 8 + 4);
    float s = fmaxf(acc[0] * dv + b0.x, 0.f) * w0.x
            + fmaxf(acc[1] * dv + b0.y, 0.f) * w0.y
            + fmaxf(acc[2] * dv + b0.z, 0.f) * w0.z
            + fmaxf(acc[3] * dv + b0.w, 0.f) * w0.w
            + fmaxf(acc[4] * dv + b1.x, 0.f) * w1.x
            + fmaxf(acc[5] * dv + b1.y, 0.f) * w1.y
            + fmaxf(acc[6] * dv + b1.z, 0.f) * w1.z
            + fmaxf(acc[7] * dv + b1.w, 0.f) * w1.w;
    s += __shfl_xor(s, 1);
    s += __shfl_xor(s, 2);
    s += __shfl_xor(s, 4);
    s += __shfl_xor(s, 8);
    if (p == 0) z[node] = s * dv;     // z = (dinv*h1).w2l
}

// ---------------- layer 2 + pool over scalars: gsum[batch[d]] += dv_d*(z_d + sum z_s) ----------------
__global__ __launch_bounds__(256) void k_gather2s(const float* __restrict__ z,
                                                  const int* __restrict__ csr_src,
                                                  const int* __restrict__ row_start,
                                                  const int* __restrict__ indeg,
                                                  const float* __restrict__ dinv,
                                                  const int* __restrict__ perm,
                                                  const int* __restrict__ batch,
                                                  float* __restrict__ gsum) {
    int nidx = blockIdx.x * blockDim.x + threadIdx.x;
    if (nidx >= N_NODES) return;
    int node = perm[nidx];
    const int beg = row_start[node];
    const int cnt = indeg[node];
    float a = z[node];
    int j = 0;
    #pragma unroll 1
    for (; j + 4 <= cnt; j += 4) {
        int i0 = csr_src[beg + j + 0];
        int i1 = csr_src[beg + j + 1];
        int i2 = csr_src[beg + j + 2];
        int i3 = csr_src[beg + j + 3];
        a += z[i0] + z[i1] + z[i2] + z[i3];
    }
    #pragma unroll 1
    for (; j < cnt; ++j)
        a += z[csr_src[beg + j]];
    atomicAdd(&gsum[batch[node]], a * dinv[node]);
}

// ---------------- final: counts via binary search on sorted batch; +c2 ----------------
__global__ void k_final(const float* __restrict__ gsum, const int* __restrict__ batch,
                        const float* __restrict__ c2, float* __restrict__ out) {
    int g = blockIdx.x * blockDim.x + threadIdx.x;
    if (g >= NGRAPHS) return;
    int lo = 0, hi = N_NODES;
    while (lo < hi) { int m = (lo + hi) >> 1; if (batch[m] < g) lo = m + 1; else hi = m; }
    int lb = lo;
    lo = 0; hi = N_NODES;
    int g1 = g + 1;
    while (lo < hi) { int m = (lo + hi) >> 1; if (batch[m] < g1) lo = m + 1; else hi = m; }
    float cnt = (float)(lo - lb);
    out[g] = gsum[g] / fmaxf(cnt, 1.0f) + c2[0];
}

extern "C" void kernel_launch(void* const* d_in, const int* in_sizes, int n_in,
                              void* d_out, int out_size, void* d_ws, size_t ws_size,
                              hipStream_t stream) {
    const float* x    = (const float*)d_in[0];
    const int*   ei   = (const int*)d_in[1];
    const int*   bat  = (const int*)d_in[2];
    const float* W1   = (const float*)d_in[3];
    const float* b1   = (const float*)d_in[4];
    const float* W2   = (const float*)d_in[5];
    const float* b2   = (const float*)d_in[6];
    const float* Wlin = (const float*)d_in[7];
    const float* blin = (const float*)d_in[8];
    float* out = (float*)d_out;

    const int* src = ei;
    const int* dst = ei + N_EDGES;

    // ---- workspace layout ----
    const size_t NF = (size_t)N_NODES * NFEAT;
    unsigned short* bufA = (unsigned short*)d_ws;          // bf16 xw1 table (dinv-scaled)
    float* z       = (float*)(bufA + NF);                  // [N] scalar layer-2 inputs
    float* dinv    = z + N_NODES;                          // [N]
    int* row_start = (int*)(dinv + N_NODES);               // [N]
    int* indeg     = row_start + N_NODES;                  // [N]
    int* perm      = indeg + N_NODES;                      // [N]
    int* bstart    = perm + N_NODES;                       // [NCB+1]
    int* gcur      = bstart + NCB + 1;                     // [NCB]
    int* bcount    = gcur + NCB;                           // [NCB]  (memset)
    float* gsum    = (float*)(bcount + NCB);               // [G]    } zeroed in k_misc
    int* dcount    = (int*)(gsum + NGRAPHS);               // [64]   }
    int* dcur      = dcount + 64;                          // [64]   }
    unsigned short* WT1 = (unsigned short*)(dcur + 64);    // [16384]
    float* w2l     = (float*)(WT1 + 128 * 128);            // [132] (c2 at [128])
    unsigned int* pairs = (unsigned int*)(w2l + 132);      // [E]
    int* csr_src   = (int*)(pairs + N_EDGES);              // [E]

    const int BS = 256;
    int gemm_blocks = (N_NODES + 127) / 128;
    int p1_blocks   = (N_EDGES + P1_EPB - 1) / P1_EPB;     // 196
    int nwaves      = (N_NODES + 3) / 4;                   // 4 nodes per wave
    int g_blocks    = (int)(((long long)nwaves * 64 + BS - 1) / BS);
    int node_blocks = (N_NODES + BS - 1) / BS;

    // ---- zero bucket counts only (rest zeroed inside k_misc) ----
    hipMemsetAsync(bcount, 0, NCB * sizeof(int), stream);

    // ---- sort pipeline ----
    k_bhist<<<256, BS, 0, stream>>>(dst, bcount);
    k_misc<<<27, BS, 0, stream>>>(bcount, bstart, gcur, W1, WT1, W2, Wlin, b2, blin, w2l,
                                  (int*)gsum);
    k_p1<<<p1_blocks, BS, 0, stream>>>(src, dst, gcur, pairs);
    k_p2<<<NCB, BS, 0, stream>>>(pairs, bstart, csr_src, row_start, indeg, dinv, dcount);
    k_dscan<<<1, 64, 0, stream>>>(dcount, dcur);
    k_dperm<<<DP_BLOCKS, BS, 0, stream>>>(indeg, dcur, perm);

    // ---- layer 1 (GEMM + gather with fused layer-2 projection to scalar z) ----
    k_gemm_mfma<<<gemm_blocks, BS, 0, stream>>>(x, WT1, dinv, bufA, N_NODES);
    k_gather1<<<g_blocks, BS, 0, stream>>>(bufA, csr_src, row_start, indeg, dinv, b1, w2l,
                                           perm, z);

    // ---- layer 2 + pool over scalar z ----
    k_gather2s<<<node_blocks, BS, 0, stream>>>(z, csr_src, row_start, indeg, dinv, perm,
                                               bat, gsum);

    // ---- final ----
    k_final<<<(NGRAPHS + BS - 1) / BS, BS, 0, stream>>>(gsum, bat, w2l + 128, out);
}

// Round 12
// 297.874 us; speedup vs baseline: 1.2172x; 1.0058x over previous
//
#include <hip/hip_runtime.h>

#define N_NODES   100000
#define N_EDGES   1600000
#define NFEAT     128
#define NGRAPHS   2048
#define CBSHIFT   8                        // 256 nodes per coarse bucket
#define NCB       ((N_NODES + 255) / 256)  // 391
#define P1_EPB    8192                     // edges per k_p1 block
#define GEMM_BLOCKS 782
#define BH_BLOCKS   256
#define DP_BLOCKS 25
#define DP_NPB    ((N_NODES + DP_BLOCKS - 1) / DP_BLOCKS)
#define G1_BLOCKS 2048
#define ZCNT      (NGRAPHS + NCB + 64 + 64 + NCB)   // gsum|alloc|dalloc|dcount|bcount

typedef __attribute__((ext_vector_type(8))) short short8;
typedef __attribute__((ext_vector_type(4))) float f32x4;

// RNE float -> bf16 (finite inputs)
__device__ __forceinline__ unsigned short f2bf(float f) {
    unsigned int u = __float_as_uint(f);
    u += 0x7FFFu + ((u >> 16) & 1u);
    return (unsigned short)(u >> 16);
}

// acc[k] += s * bf16[k]  (8 bf16 packed in uint4)
__device__ __forceinline__ void acc8s(float* acc, uint4 v, float s) {
    acc[0] = fmaf(s, __uint_as_float(v.x << 16), acc[0]);
    acc[1] = fmaf(s, __uint_as_float(v.x & 0xFFFF0000u), acc[1]);
    acc[2] = fmaf(s, __uint_as_float(v.y << 16), acc[2]);
    acc[3] = fmaf(s, __uint_as_float(v.y & 0xFFFF0000u), acc[3]);
    acc[4] = fmaf(s, __uint_as_float(v.z << 16), acc[4]);
    acc[5] = fmaf(s, __uint_as_float(v.z & 0xFFFF0000u), acc[5]);
    acc[6] = fmaf(s, __uint_as_float(v.w << 16), acc[6]);
    acc[7] = fmaf(s, __uint_as_float(v.w & 0xFFFF0000u), acc[7]);
}

// ---------------- multi-role setup: 0-15 WT1 prep, 16 w2l, 17+ zero accumulators ----------------
__global__ __launch_bounds__(256) void k_misc(const float* __restrict__ W1,
                                              unsigned short* __restrict__ WT1,
                                              const float* __restrict__ W2,
                                              const float* __restrict__ Wlin,
                                              const float* __restrict__ b2,
                                              const float* __restrict__ blin,
                                              float* __restrict__ w2l,
                                              int* __restrict__ zeros) {
    const int blk = blockIdx.x;
    const int t = threadIdx.x;
    if (blk < 16) {
        int base = blk * 1024 + t * 4;
        #pragma unroll
        for (int q = 0; q < 4; ++q) {
            int i = base + q;
            int n = i >> 7, k = i & 127;
            WT1[i] = f2bf(W1[k * 128 + n]);
        }
    } else if (blk == 16) {
        if (t < 128) {
            float s = 0.f;
            for (int j = 0; j < 128; ++j) s += W2[t * 128 + j] * Wlin[j];
            w2l[t] = s;
            if (t == 0) {
                float c = 0.f;
                for (int j = 0; j < 128; ++j) c += b2[j] * Wlin[j];
                w2l[128] = c + blin[0];
            }
        }
    } else {
        int i = (blk - 17) * 256 + t;
        if (i < ZCNT) zeros[i] = 0;
    }
}

// ---------------- fused: LDS-free MFMA GEMM (unscaled)  ||  coarse bucket histogram ----------------
__global__ __launch_bounds__(256) void k_gemm_bhist(const float* __restrict__ X,
                                                    const unsigned short* __restrict__ WT,
                                                    unsigned short* __restrict__ C,
                                                    const int* __restrict__ dst,
                                                    int* __restrict__ bcount) {
    if (blockIdx.x >= GEMM_BLOCKS) {
        // ---- histogram part ----
        __shared__ int h[NCB];
        for (int i = threadIdx.x; i < NCB; i += 256) h[i] = 0;
        __syncthreads();
        int b = blockIdx.x - GEMM_BLOCKS;
        int stride = BH_BLOCKS * 256;
        for (int e = b * 256 + threadIdx.x; e < N_EDGES; e += stride)
            atomicAdd(&h[dst[e] >> CBSHIFT], 1);
        __syncthreads();
        for (int i = threadIdx.x; i < NCB; i += 256) {
            int v = h[i];
            if (v) atomicAdd(&bcount[i], v);
        }
        return;
    }
    // ---- GEMM part: C[r,:] = bf16(X[r,:] @ W1), no LDS, B frags via L2 ----
    const int tid  = threadIdx.x;
    const int R0   = blockIdx.x * 128;
    const int wv   = tid >> 6;
    const int lane = tid & 63;
    const int m16  = lane & 15;
    const int quad = lane >> 4;
    const int r0 = R0 + wv * 32 + m16;
    const int r1 = r0 + 16;
    const bool ok0 = r0 < N_NODES, ok1 = r1 < N_NODES;

    f32x4 acc[2][8] = {};
    #pragma unroll
    for (int ks = 0; ks < 4; ++ks) {
        const int k0 = ks * 32 + quad * 8;
        short8 a0 = {}, a1 = {};
        if (ok0) {
            float4 f0 = *(const float4*)(X + (size_t)r0 * NFEAT + k0);
            float4 f1 = *(const float4*)(X + (size_t)r0 * NFEAT + k0 + 4);
            a0[0] = (short)f2bf(f0.x); a0[1] = (short)f2bf(f0.y);
            a0[2] = (short)f2bf(f0.z); a0[3] = (short)f2bf(f0.w);
            a0[4] = (short)f2bf(f1.x); a0[5] = (short)f2bf(f1.y);
            a0[6] = (short)f2bf(f1.z); a0[7] = (short)f2bf(f1.w);
        }
        if (ok1) {
            float4 f0 = *(const float4*)(X + (size_t)r1 * NFEAT + k0);
            float4 f1 = *(const float4*)(X + (size_t)r1 * NFEAT + k0 + 4);
            a1[0] = (short)f2bf(f0.x); a1[1] = (short)f2bf(f0.y);
            a1[2] = (short)f2bf(f0.z); a1[3] = (short)f2bf(f0.w);
            a1[4] = (short)f2bf(f1.x); a1[5] = (short)f2bf(f1.y);
            a1[6] = (short)f2bf(f1.z); a1[7] = (short)f2bf(f1.w);
        }
        #pragma unroll
        for (int ct = 0; ct < 8; ++ct) {
            short8 bb = *(const short8*)(WT + (ct * 16 + m16) * 128 + k0);
            acc[0][ct] = __builtin_amdgcn_mfma_f32_16x16x32_bf16(a0, bb, acc[0][ct], 0, 0, 0);
            acc[1][ct] = __builtin_amdgcn_mfma_f32_16x16x32_bf16(a1, bb, acc[1][ct], 0, 0, 0);
        }
    }
    #pragma unroll
    for (int t2 = 0; t2 < 2; ++t2) {
        int rbase = R0 + wv * 32 + t2 * 16 + quad * 4;
        #pragma unroll
        for (int reg = 0; reg < 4; ++reg) {
            int gr = rbase + reg;
            if (gr < N_NODES) {
                #pragma unroll
                for (int ct = 0; ct < 8; ++ct)
                    C[(size_t)gr * NFEAT + ct * 16 + m16] = f2bf(acc[t2][ct][reg]);
            }
        }
    }
}

// ---------------- pass 1: self-scanning block-ranked scatter ----------------
__global__ __launch_bounds__(256) void k_p1(const int* __restrict__ src,
                                            const int* __restrict__ dst,
                                            const int* __restrict__ bcount,
                                            int* __restrict__ bstart,
                                            int* __restrict__ alloc,
                                            unsigned int* __restrict__ pairs) {
    __shared__ int hist[NCB], base[NCB], cur[NCB], bst[NCB], s[256];
    const int t = threadIdx.x;
    for (int i = t; i < NCB; i += 256) { hist[i] = 0; cur[i] = 0; }
    // local exclusive scan of bcount
    int v0 = (2 * t < NCB) ? bcount[2 * t] : 0;
    int v1 = (2 * t + 1 < NCB) ? bcount[2 * t + 1] : 0;
    int local = v0 + v1;
    s[t] = local;
    __syncthreads();
    for (int off = 1; off < 256; off <<= 1) {
        int x = (t >= off) ? s[t - off] : 0;
        __syncthreads();
        s[t] += x;
        __syncthreads();
    }
    int excl = s[t] - local;
    if (2 * t < NCB)     bst[2 * t] = excl;
    if (2 * t + 1 < NCB) bst[2 * t + 1] = excl + v0;
    if (blockIdx.x == 0) {
        if (2 * t < NCB)     bstart[2 * t] = excl;
        if (2 * t + 1 < NCB) bstart[2 * t + 1] = excl + v0;
        if (t == 255) bstart[NCB] = s[255];
    }
    __syncthreads();
    const int e0 = blockIdx.x * P1_EPB;
    const int e1 = min(e0 + P1_EPB, N_EDGES);
    for (int e = e0 + t; e < e1; e += 256)
        atomicAdd(&hist[dst[e] >> CBSHIFT], 1);
    __syncthreads();
    for (int i = t; i < NCB; i += 256) {
        int c = hist[i];
        base[i] = c ? (bst[i] + atomicAdd(&alloc[i], c)) : 0;
    }
    __syncthreads();
    for (int e = e0 + t; e < e1; e += 256) {
        int d = dst[e];
        int b = d >> CBSHIFT;
        int r = atomicAdd(&cur[b], 1);
        pairs[base[b] + r] = (unsigned int)src[e] | ((unsigned int)(d & 255) << 17);
    }
}

// ---------------- pass 2: per-bucket sort -> csr_src, row_start, indeg, dinv (+deg hist) ----------------
__global__ __launch_bounds__(256) void k_p2(const unsigned int* __restrict__ pairs,
                                            const int* __restrict__ bstart,
                                            int* __restrict__ csr_src,
                                            int* __restrict__ row_start,
                                            int* __restrict__ indeg,
                                            float* __restrict__ dinv,
                                            int* __restrict__ dcount) {
    __shared__ int hist[256], sst[256], cur[256], s[256], dh[64];
    const int b = blockIdx.x;
    const int t = threadIdx.x;
    const int beg = bstart[b];
    const int end = bstart[b + 1];
    hist[t] = 0; cur[t] = 0;
    if (t < 64) dh[t] = 0;
    __syncthreads();
    for (int i = beg + t; i < end; i += 256)
        atomicAdd(&hist[pairs[i] >> 17], 1);
    __syncthreads();
    int v = hist[t];
    s[t] = v;
    __syncthreads();
    for (int off = 1; off < 256; off <<= 1) {
        int x = (t >= off) ? s[t - off] : 0;
        __syncthreads();
        s[t] += x;
        __syncthreads();
    }
    sst[t] = s[t] - v;
    __syncthreads();
    {
        int node = (b << CBSHIFT) + t;
        if (node < N_NODES) {
            row_start[node] = beg + sst[t];
            indeg[node] = v;
            dinv[node] = rsqrtf((float)v + 1.0f);
            atomicAdd(&dh[63 - min(v, 63)], 1);
        }
    }
    for (int i = beg + t; i < end; i += 256) {
        unsigned int pv = pairs[i];
        int dl = pv >> 17;
        int r = atomicAdd(&cur[dl], 1);
        csr_src[beg + sst[dl] + r] = (int)(pv & 0x1FFFFu);
    }
    __syncthreads();
    if (t < 64 && dh[t]) atomicAdd(&dcount[t], dh[t]);
}

// ---------------- degree permutation (descending), self-scanning ----------------
__global__ __launch_bounds__(256) void k_dperm(const int* __restrict__ indeg,
                                               const int* __restrict__ dcount,
                                               int* __restrict__ dalloc,
                                               int* __restrict__ perm) {
    __shared__ int h[64], base[64], cur[64], s[64];
    const int t = threadIdx.x;
    int v = 0;
    if (t < 64) { h[t] = 0; cur[t] = 0; v = dcount[t]; s[t] = v; }
    __syncthreads();
    for (int off = 1; off < 64; off <<= 1) {
        int x = (t >= off && t < 64) ? s[t - off] : 0;
        __syncthreads();
        if (t < 64) s[t] += x;
        __syncthreads();
    }
    int myst = (t < 64) ? s[t] - v : 0;
    const int i0 = blockIdx.x * DP_NPB;
    const int i1 = min(i0 + DP_NPB, N_NODES);
    for (int i = i0 + t; i < i1; i += 256)
        atomicAdd(&h[63 - min(indeg[i], 63)], 1);
    __syncthreads();
    if (t < 64) {
        int c = h[t];
        base[t] = c ? (myst + atomicAdd(&dalloc[t], c)) : 0;
    }
    __syncthreads();
    for (int i = i0 + t; i < i1; i += 256) {
        int bin = 63 - min(indeg[i], 63);
        int r = atomicAdd(&cur[bin], 1);
        perm[base[bin] + r] = i;
    }
}

// ---------------- gather layer 1 (per-edge dinv) + fused z projection; persistent ----------------
__global__ __launch_bounds__(256) void k_gather1(const unsigned short* __restrict__ xwb,
                                                 const int* __restrict__ csr_src,
                                                 const int* __restrict__ row_start,
                                                 const int* __restrict__ indeg,
                                                 const float* __restrict__ dinv,
                                                 const float* __restrict__ b,
                                                 const float* __restrict__ w2l,
                                                 const int* __restrict__ perm,
                                                 float* __restrict__ z) {
    const int lane  = threadIdx.x & 63;
    const int p     = lane & 15;
    const int gbase = lane & 48;           // group base lane within wave
    const int ngroups = G1_BLOCKS * 16;
    int gid = blockIdx.x * 16 + (threadIdx.x >> 4);
    const uint4* tab = (const uint4*)xwb;
    float4 b0 = *(const float4*)(b + p * 8);
    float4 b1 = *(const float4*)(b + p * 8 + 4);
    float4 w0 = *(const float4*)(w2l + p * 8);
    float4 w1 = *(const float4*)(w2l + p * 8 + 4);

    for (int nidx = gid; nidx < N_NODES; nidx += ngroups) {
        int node = perm[nidx];
        const int beg = row_start[node];
        const int cnt = indeg[node];
        float dvn = dinv[node];
        float acc[8] = {};
        acc8s(acc, tab[(size_t)node * 16 + p], dvn);     // self loop
        int j = 0;
        #pragma unroll 1
        for (; j + 8 <= cnt; j += 8) {
            int   my   = csr_src[beg + j + (p & 7)];     // one idx load per lane
            float mydv = dinv[my];                       // one dinv load per lane
            uint4 v[8];
            #pragma unroll
            for (int q = 0; q < 8; ++q) {
                int idx = __shfl(my, gbase + q);
                v[q] = tab[(size_t)idx * 16 + p];
            }
            #pragma unroll
            for (int q = 0; q < 8; ++q) {
                float sv = __shfl(mydv, gbase + q);
                acc8s(acc, v[q], sv);
            }
        }
        #pragma unroll 1
        for (; j < cnt; ++j) {
            int idx = csr_src[beg + j];
            float sv = dinv[idx];
            acc8s(acc, tab[(size_t)idx * 16 + p], sv);
        }
        float s = fmaxf(acc[0] * dvn + b0.x, 0.f) * w0.x
                + fmaxf(acc[1] * dvn + b0.y, 0.f) * w0.y
                + fmaxf(acc[2] * dvn + b0.z, 0.f) * w0.z
                + fmaxf(acc[3] * dvn + b0.w, 0.f) * w0.w
                + fmaxf(acc[4] * dvn + b1.x, 0.f) * w1.x
                + fmaxf(acc[5] * dvn + b1.y, 0.f) * w1.y
                + fmaxf(acc[6] * dvn + b1.z, 0.f) * w1.z
                + fmaxf(acc[7] * dvn + b1.w, 0.f) * w1.w;
        s += __shfl_xor(s, 1);
        s += __shfl_xor(s, 2);
        s += __shfl_xor(s, 4);
        s += __shfl_xor(s, 8);
        if (p == 0) z[node] = s * dvn;                   // z = dinv_node * (h1 . w2l)
    }
}

// ---------------- layer 2 + pool over scalars ----------------
__global__ __launch_bounds__(256) void k_gather2s(const float* __restrict__ z,
                                                  const int* __restrict__ csr_src,
                                                  const int* __restrict__ row_start,
                                                  const int* __restrict__ indeg,
                                                  const float* __restrict__ dinv,
                                                  const int* __restrict__ perm,
                                                  const int* __restrict__ batch,
                                                  float* __restrict__ gsum) {
    int nidx = blockIdx.x * blockDim.x + threadIdx.x;
    if (nidx >= N_NODES) return;
    int node = perm[nidx];
    const int beg = row_start[node];
    const int cnt = indeg[node];
    float a = z[node];
    int j = 0;
    #pragma unroll 1
    for (; j + 4 <= cnt; j += 4) {
        int i0 = csr_src[beg + j + 0];
        int i1 = csr_src[beg + j + 1];
        int i2 = csr_src[beg + j + 2];
        int i3 = csr_src[beg + j + 3];
        a += z[i0] + z[i1] + z[i2] + z[i3];
    }
    #pragma unroll 1
    for (; j < cnt; ++j)
        a += z[csr_src[beg + j]];
    atomicAdd(&gsum[batch[node]], a * dinv[node]);
}

// ---------------- final: counts via binary search on sorted batch; +c2 ----------------
__global__ void k_final(const float* __restrict__ gsum, const int* __restrict__ batch,
                        const float* __restrict__ c2, float* __restrict__ out) {
    int g = blockIdx.x * blockDim.x + threadIdx.x;
    if (g >= NGRAPHS) return;
    int lo = 0, hi = N_NODES;
    while (lo < hi) { int m = (lo + hi) >> 1; if (batch[m] < g) lo = m + 1; else hi = m; }
    int lb = lo;
    lo = 0; hi = N_NODES;
    int g1 = g + 1;
    while (lo < hi) { int m = (lo + hi) >> 1; if (batch[m] < g1) lo = m + 1; else hi = m; }
    float cnt = (float)(lo - lb);
    out[g] = gsum[g] / fmaxf(cnt, 1.0f) + c2[0];
}

extern "C" void kernel_launch(void* const* d_in, const int* in_sizes, int n_in,
                              void* d_out, int out_size, void* d_ws, size_t ws_size,
                              hipStream_t stream) {
    const float* x    = (const float*)d_in[0];
    const int*   ei   = (const int*)d_in[1];
    const int*   bat  = (const int*)d_in[2];
    const float* W1   = (const float*)d_in[3];
    const float* b1   = (const float*)d_in[4];
    const float* W2   = (const float*)d_in[5];
    const float* b2   = (const float*)d_in[6];
    const float* Wlin = (const float*)d_in[7];
    const float* blin = (const float*)d_in[8];
    float* out = (float*)d_out;

    const int* src = ei;
    const int* dst = ei + N_EDGES;

    // ---- workspace layout ----
    const size_t NF = (size_t)N_NODES * NFEAT;
    unsigned short* bufA = (unsigned short*)d_ws;          // bf16 xw1 table (unscaled)
    float* z       = (float*)(bufA + NF);                  // [N]
    float* dinv    = z + N_NODES;                          // [N]
    int* row_start = (int*)(dinv + N_NODES);               // [N]
    int* indeg     = row_start + N_NODES;                  // [N]
    int* perm      = indeg + N_NODES;                      // [N]
    int* bstart    = perm + N_NODES;                       // [NCB+1]
    // zeroed-by-misc region (contiguous): gsum | alloc | dalloc | dcount | bcount
    float* gsum    = (float*)(bstart + NCB + 1);           // [G]
    int* alloc     = (int*)(gsum + NGRAPHS);               // [NCB]
    int* dalloc    = alloc + NCB;                          // [64]
    int* dcount    = dalloc + 64;                          // [64]
    int* bcount    = dcount + 64;                          // [NCB]
    unsigned short* WT1 = (unsigned short*)(bcount + NCB); // [16384]
    float* w2l     = (float*)(WT1 + 128 * 128);            // [132] (c2 at [128])
    unsigned int* pairs = (unsigned int*)(w2l + 132);      // [E]
    int* csr_src   = (int*)(pairs + N_EDGES);              // [E]

    const int BS = 256;
    int p1_blocks   = (N_EDGES + P1_EPB - 1) / P1_EPB;     // 196
    int node_blocks = (N_NODES + BS - 1) / BS;
    int misc_blocks = 17 + (ZCNT + BS - 1) / BS;           // 17 + 12 = 29

    // ---- setup (weights + zeroing), then fused GEMM || bucket histogram ----
    k_misc<<<misc_blocks, BS, 0, stream>>>(W1, WT1, W2, Wlin, b2, blin, w2l, (int*)gsum);
    k_gemm_bhist<<<GEMM_BLOCKS + BH_BLOCKS, BS, 0, stream>>>(x, WT1, bufA, dst, bcount);

    // ---- CSR build ----
    k_p1<<<p1_blocks, BS, 0, stream>>>(src, dst, bcount, bstart, alloc, pairs);
    k_p2<<<NCB, BS, 0, stream>>>(pairs, bstart, csr_src, row_start, indeg, dinv, dcount);
    k_dperm<<<DP_BLOCKS, BS, 0, stream>>>(indeg, dcount, dalloc, perm);

    // ---- layer 1 gather (+ fused layer-2 projection to scalar z) ----
    k_gather1<<<G1_BLOCKS, BS, 0, stream>>>(bufA, csr_src, row_start, indeg, dinv, b1, w2l,
                                            perm, z);

    // ---- layer 2 + pool over scalar z ----
    k_gather2s<<<node_blocks, BS, 0, stream>>>(z, csr_src, row_start, indeg, dinv, perm,
                                               bat, gsum);

    // ---- final ----
    k_final<<<(NGRAPHS + BS - 1) / BS, BS, 0, stream>>>(gsum, bat, w2l + 128, out);
}